// Round 17
// baseline (188.201 us; speedup 1.0000x reference)
//
#include <hip/hip_runtime.h>
#include <hip/hip_bf16.h>
#include <hip/hip_fp16.h>

#define NN    50000
#define NE    800000
#define ETOT  (NE + NN)
#define D     128
#define NB    ((NN + 255) / 256)     // 196 scan blocks
#define HB    256                    // hist/scatter partitions
#define EPB   3328                   // edges per partition = 13*256; HB*EPB >= ETOT
#define NNP   50176                  // padded per-partition table stride (bytes)
#define NNPW  (NNP / 4)              // u32 words per histogram row

typedef _Float16 f16x8 __attribute__((ext_vector_type(8)));
typedef float    f32x4 __attribute__((ext_vector_type(4)));

__device__ __forceinline__ float gelu_fast(float x) {
    float x2 = x * x;
    float z2 = x * fmaf(x2, 0.07135483f, 1.5957691f);   // 2z
    float e  = __expf(z2);
    return x - __fdividef(x, e + 1.0f);
}

// v_fma_mix_f32: acc += (f32)f16(lo/hi of HH) * WW
#define FMAMIX_LO(ACC, HH, WW) \
    asm("v_fma_mix_f32 %0, %1, %2, %0 op_sel_hi:[1,0,0]" : "+v"(ACC) : "v"(HH), "v"(WW))
#define FMAMIX_HI(ACC, HH, WW) \
    asm("v_fma_mix_f32 %0, %1, %2, %0 op_sel:[1,0,0] op_sel_hi:[1,0,0]" : "+v"(ACC) : "v"(HH), "v"(WW))

// ---------------- init: wasd | W^T fp16 ----------------

__global__ __launch_bounds__(256) void init_k(
        const float* __restrict__ W,
        const float* __restrict__ asrc, const float* __restrict__ adst,
        float* __restrict__ wasd, __half* __restrict__ WT) {
    int b = blockIdx.x, t = threadIdx.x;
    if (b < 3) {
        int l = b;
        int k = t & 127, which = t >> 7;
        const float* wr = W + (size_t)l * 16384 + (size_t)k * 128;
        const float* av = (which ? adst : asrc) + (size_t)l * 128;
        float s = 0.f;
        #pragma unroll 4
        for (int c = 0; c < 128; ++c) s += wr[c] * av[c];
        wasd[l * 256 + which * 128 + k] = s;
    } else {
        int i = (b - 3) * 256 + t;           // 0..49151
        int l = i >> 14, r = i & 16383;
        int k = r >> 7, c = r & 127;
        WT[(size_t)l * 16384 + (size_t)c * 128 + k] =
            __float2half_rn(W[(size_t)l * 16384 + (size_t)k * 128 + c]);
    }
}

// ------------- gemm core: MFMA fp16, full [NN][128] output, fused alphas -------------

template <int AIN32>
__device__ __forceinline__ void gemm_body(
        int b2, int t, const void* __restrict__ A, const __half* __restrict__ WT,
        const float* __restrict__ wasd, __half* __restrict__ XP,
        float* __restrict__ alpha_s, float* __restrict__ alpha_d, __half* Bs) {
    #pragma unroll
    for (int it = 0; it < 8; ++it) {
        int bb = it * 4096 + t * 16;
        int c = bb >> 8;
        int swz = bb ^ ((c & 7) << 4);
        *(uint4*)((char*)Bs + swz) = *(const uint4*)((const char*)WT + bb);
    }
    __syncthreads();

    int w = t >> 6, lane = t & 63;
    int r0 = (b2 >> 1) * 256 + w * 64;
    int c0 = (b2 & 1) * 64;
    int lr = lane & 15, lg = lane >> 4;
    bool doalpha = (b2 & 1) == 0;

    f32x4 acc[4][4];
    #pragma unroll
    for (int i = 0; i < 4; ++i)
        #pragma unroll
        for (int j = 0; j < 4; ++j)
            acc[i][j] = (f32x4){0.f, 0.f, 0.f, 0.f};

    float ps[4] = {0, 0, 0, 0}, pd[4] = {0, 0, 0, 0};

    #pragma unroll
    for (int ks = 0; ks < 4; ++ks) {
        f16x8 bf[4];
        #pragma unroll
        for (int ct = 0; ct < 4; ++ct) {
            int c  = c0 + ct * 16 + lr;
            int kb = ks * 64 + lg * 16;
            int addr = c * 256 + (kb ^ ((c & 7) << 4));
            bf[ct] = *(const f16x8*)((const char*)Bs + addr);
        }
        float4 s0, s1, d0, d1;
        if (doalpha) {
            const float* wsp = wasd + ks * 32 + lg * 8;
            s0 = *(const float4*)(wsp);       s1 = *(const float4*)(wsp + 4);
            d0 = *(const float4*)(wsp + 128); d1 = *(const float4*)(wsp + 132);
        }
        #pragma unroll
        for (int rt = 0; rt < 4; ++rt) {
            int row = r0 + rt * 16 + lr;
            int rc  = row < NN ? row : NN - 1;
            f16x8 af;
            float4 f0, f1;
            if (AIN32) {
                const float* ap = (const float*)A + (size_t)rc * D + ks * 32 + lg * 8;
                f0 = *(const float4*)ap;
                f1 = *(const float4*)(ap + 4);
                af[0] = (_Float16)f0.x; af[1] = (_Float16)f0.y;
                af[2] = (_Float16)f0.z; af[3] = (_Float16)f0.w;
                af[4] = (_Float16)f1.x; af[5] = (_Float16)f1.y;
                af[6] = (_Float16)f1.z; af[7] = (_Float16)f1.w;
            } else {
                af = *(const f16x8*)((const char*)A + (size_t)rc * 256 + ks * 64 + lg * 16);
                if (doalpha) {
                    f0 = make_float4((float)af[0], (float)af[1], (float)af[2], (float)af[3]);
                    f1 = make_float4((float)af[4], (float)af[5], (float)af[6], (float)af[7]);
                }
            }
            if (doalpha) {
                ps[rt] += f0.x*s0.x + f0.y*s0.y + f0.z*s0.z + f0.w*s0.w
                        + f1.x*s1.x + f1.y*s1.y + f1.z*s1.z + f1.w*s1.w;
                pd[rt] += f0.x*d0.x + f0.y*d0.y + f0.z*d0.z + f0.w*d0.w
                        + f1.x*d1.x + f1.y*d1.y + f1.z*d1.z + f1.w*d1.w;
            }
            #pragma unroll
            for (int ct = 0; ct < 4; ++ct)
                acc[rt][ct] = __builtin_amdgcn_mfma_f32_16x16x32_f16(
                                  af, bf[ct], acc[rt][ct], 0, 0, 0);
        }
    }

    #pragma unroll
    for (int rt = 0; rt < 4; ++rt) {
        #pragma unroll
        for (int q = 0; q < 4; ++q) {
            int row = r0 + rt * 16 + lg * 4 + q;
            if (row < NN) {
                #pragma unroll
                for (int ct = 0; ct < 4; ++ct)
                    XP[(size_t)row * D + c0 + ct * 16 + lr] = __float2half_rn(acc[rt][ct][q]);
            }
        }
    }

    if (doalpha) {
        #pragma unroll
        for (int rt = 0; rt < 4; ++rt) {
            float p = ps[rt], dq = pd[rt];
            p  += __shfl_xor(p, 16);  p  += __shfl_xor(p, 32);
            dq += __shfl_xor(dq, 16); dq += __shfl_xor(dq, 32);
            int row = r0 + rt * 16 + lr;
            if (lane < 16 && row < NN) { alpha_s[row] = p; alpha_d[row] = dq; }
        }
    }
}

// ------- histg: LDS-privatized histogram (blocks < HB) | gemm-0 (blocks >= HB) -------

__global__ __launch_bounds__(256) void histg_k(
        const int* __restrict__ dst_arr, unsigned char* __restrict__ rank8,
        unsigned int* __restrict__ counts8,
        const float* __restrict__ x, const __half* __restrict__ WT,
        const float* __restrict__ wasd, __half* __restrict__ XPH,
        float* __restrict__ alpha_s, float* __restrict__ alpha_d) {
    __shared__ __align__(16) unsigned char shmem[NNPW * 4];   // 49 KB (hist) / 32 KB (gemm)
    int b = blockIdx.x, t = threadIdx.x;
    if (b < HB) {
        unsigned int* h = (unsigned int*)shmem;
        for (int i = t; i < NNPW; i += 256) h[i] = 0u;
        __syncthreads();
        int base = b * EPB;
        #pragma unroll
        for (int it = 0; it < 13; ++it) {
            int e = base + it * 256 + t;
            if (e < ETOT) {
                int d = (e < NE) ? dst_arr[e] : (e - NE);
                int sh = (d & 3) * 8;
                unsigned int old = atomicAdd(&h[d >> 2], 1u << sh);
                rank8[e] = (unsigned char)((old >> sh) & 0xffu);
            }
        }
        __syncthreads();
        unsigned int* crow = counts8 + (size_t)b * NNPW;
        for (int i = t; i < NNPW; i += 256) crow[i] = h[i];
    } else {
        gemm_body<1>(b - HB, t, x, WT, wasd, XPH, alpha_s, alpha_d, (__half*)shmem);
    }
}

// ------- merge: per-dst prefix over partitions -> boff8[p][d], totals -> counts[d] -------

__global__ __launch_bounds__(256) void merge_k(
        const unsigned char* __restrict__ counts8, unsigned char* __restrict__ boff8,
        int* __restrict__ counts) {
    __shared__ int segtot[4][64];
    int t = threadIdx.x;
    int dl = t & 63, seg = t >> 6;
    int d = blockIdx.x * 64 + dl;
    const unsigned char* cp = counts8 + (size_t)seg * 64 * NNP + d;
    int partial = 0;
    #pragma unroll 8
    for (int p = 0; p < 64; ++p) partial += (int)cp[(size_t)p * NNP];
    segtot[seg][dl] = partial;
    __syncthreads();
    int base = 0;
    if (seg > 0) base += segtot[0][dl];
    if (seg > 1) base += segtot[1][dl];
    if (seg > 2) base += segtot[2][dl];
    unsigned char* bp = boff8 + (size_t)seg * 64 * NNP + d;
    int acc = base;
    for (int p = 0; p < 64; ++p) {
        bp[(size_t)p * NNP] = (unsigned char)acc;
        acc += (int)cp[(size_t)p * NNP];
    }
    if (seg == 3 && d < NN) counts[d] = acc;
}

// ---------------- scans (proven) ----------------

__global__ void scan1_k(const int* __restrict__ counts, int* __restrict__ blk_sums) {
    __shared__ int sm[4];
    int i = blockIdx.x * 256 + threadIdx.x;
    int v = (i < NN) ? counts[i] : 0;
    #pragma unroll
    for (int o = 32; o; o >>= 1) v += __shfl_xor(v, o);
    if ((threadIdx.x & 63) == 0) sm[threadIdx.x >> 6] = v;
    __syncthreads();
    if (threadIdx.x == 0) blk_sums[blockIdx.x] = sm[0] + sm[1] + sm[2] + sm[3];
}

__global__ void scan23_k(const int* __restrict__ counts, const int* __restrict__ blk_sums,
                         int* __restrict__ row_ptr) {
    __shared__ int s[256];
    __shared__ int boff_sh;
    int t = threadIdx.x, bid = blockIdx.x;
    if (t < 64) {
        int acc = 0;
        for (int i = t; i < bid; i += 64) acc += blk_sums[i];
        #pragma unroll
        for (int o = 32; o; o >>= 1) acc += __shfl_xor(acc, o);
        if (t == 0) boff_sh = acc;
    }
    __syncthreads();
    int boff = boff_sh;
    int i = bid * 256 + t;
    int v = (i < NN) ? counts[i] : 0;
    s[t] = v;
    __syncthreads();
    for (int off = 1; off < 256; off <<= 1) {
        int x = (t >= off) ? s[t - off] : 0;
        __syncthreads();
        s[t] += x;
        __syncthreads();
    }
    int excl = s[t] - v + boff;
    if (i < NN) row_ptr[i] = excl;
    if (bid == NB - 1 && t == 255) row_ptr[NN] = s[255] + boff;
}

// ---------------- scatter: standalone, atomic-free, full occupancy ----------------

__global__ __launch_bounds__(256) void scatter2_k(
        const int* __restrict__ src_arr, const int* __restrict__ dst_arr,
        const unsigned char* __restrict__ rank8, const unsigned char* __restrict__ boff8,
        const int* __restrict__ row_ptr, int* __restrict__ srcs) {
    int b = blockIdx.x, t = threadIdx.x;
    const unsigned char* brow = boff8 + (size_t)b * NNP;
    int base = b * EPB;
    #pragma unroll
    for (int it = 0; it < 13; ++it) {
        int e = base + it * 256 + t;
        if (e < ETOT) {
            int d, s;
            if (e < NE) { d = dst_arr[e]; s = src_arr[e]; }
            else        { d = e - NE;    s = e - NE; }
            srcs[row_ptr[d] + (int)brow[d] + (int)rank8[e]] = s;
        }
    }
}

// ---------------- standalone gemm (layers 1, 2) ----------------

__global__ __launch_bounds__(256) void gemm_k(
        const __half* __restrict__ TH, const __half* __restrict__ WT,
        const float* __restrict__ wasd, __half* __restrict__ XPH,
        float* __restrict__ alpha_s, float* __restrict__ alpha_d) {
    __shared__ __half Bs[D * D];
    gemm_body<0>(blockIdx.x, threadIdx.x, TH, WT, wasd, XPH, alpha_s, alpha_d, Bs);
}

// ------- aggregation: gather fp16 [NN][128], ALWAYS 4-deep pipelined, fma_mix ----

template <int OUT32, int GELU>
__global__ __launch_bounds__(256) void agg_u_k(
        const int* __restrict__ row_ptr, const int* __restrict__ srcs,
        const float* __restrict__ alpha_s, const float* __restrict__ alpha_d,
        const __half* __restrict__ XPH, const float* __restrict__ bias,
        void* __restrict__ outp) {
    __shared__ float xch[4][128];
    int wv = threadIdx.x >> 6;
    int n = (blockIdx.x * blockDim.x + threadIdx.x) >> 6;
    int lane = threadIdx.x & 63;
    int beg = row_ptr[n], end = row_ptr[n + 1], deg = end - beg;
    float ad = alpha_d[n];
    int qw = lane >> 4, q = lane & 15;

    float2 fin;

    if (deg <= 64) {
        int sreg = 0;                    // lanes >= deg keep row 0 (L2-hot), w=0
        float e = -3.4e38f;
        if (lane < deg) {
            sreg = srcs[beg + lane];
            float v = alpha_s[sreg] + ad;
            e = v > 0.f ? v : 0.2f * v;
        }
        float m = e;
        #pragma unroll
        for (int o = 32; o; o >>= 1) m = fmaxf(m, __shfl_xor(m, o));
        float w = (lane < deg) ? __expf(e - m) : 0.f;
        float denom = w;
        #pragma unroll
        for (int o = 32; o; o >>= 1) denom += __shfl_xor(denom, o);

        float acc[8] = {0,0,0,0,0,0,0,0};
        int dgr = (deg + 15) & ~15;      // round to 16 -> every iteration is 4-deep
        const char* xb = (const char*)XPH;
        int qb = q << 4;
        #define PROC(UU, WW)                                                      \
            {                                                                     \
                FMAMIX_LO(acc[0], (UU).x, (WW)); FMAMIX_HI(acc[1], (UU).x, (WW)); \
                FMAMIX_LO(acc[2], (UU).y, (WW)); FMAMIX_HI(acc[3], (UU).y, (WW)); \
                FMAMIX_LO(acc[4], (UU).z, (WW)); FMAMIX_HI(acc[5], (UU).z, (WW)); \
                FMAMIX_LO(acc[6], (UU).w, (WW)); FMAMIX_HI(acc[7], (UU).w, (WW)); \
            }
        for (int j = 0; j < dgr; j += 16) {
            int   s0 = __shfl(sreg, j + qw);       float w0 = __shfl(w, j + qw);
            int   s1 = __shfl(sreg, j + 4 + qw);   float w1 = __shfl(w, j + 4 + qw);
            int   s2 = __shfl(sreg, j + 8 + qw);   float w2 = __shfl(w, j + 8 + qw);
            int   s3 = __shfl(sreg, j + 12 + qw);  float w3 = __shfl(w, j + 12 + qw);
            uint4 u0 = *(const uint4*)(xb + ((s0 << 8) + qb));
            uint4 u1 = *(const uint4*)(xb + ((s1 << 8) + qb));
            uint4 u2 = *(const uint4*)(xb + ((s2 << 8) + qb));
            uint4 u3 = *(const uint4*)(xb + ((s3 << 8) + qb));
            PROC(u0, w0) PROC(u1, w1) PROC(u2, w2) PROC(u3, w3)
        }
        #undef PROC
        #pragma unroll
        for (int f = 0; f < 8; ++f) {
            acc[f] += __shfl_xor(acc[f], 16);
            acc[f] += __shfl_xor(acc[f], 32);
        }
        if (lane < 16) {
            float4* p = (float4*)&xch[wv][q * 8];
            p[0] = make_float4(acc[0], acc[1], acc[2], acc[3]);
            p[1] = make_float4(acc[4], acc[5], acc[6], acc[7]);
        }
        __asm__ volatile("s_waitcnt lgkmcnt(0)" ::: "memory");
        __builtin_amdgcn_sched_barrier(0);
        float2 a2 = *(const float2*)&xch[wv][2 * lane];
        float inv = 1.f / (denom + 1e-16f);
        fin.x = a2.x * inv;
        fin.y = a2.y * inv;
    } else {
        float m = -3.4e38f;
        for (int i = beg + lane; i < end; i += 64) {
            int s = srcs[i];
            float v = alpha_s[s] + ad; v = v > 0.f ? v : 0.2f * v;
            m = fmaxf(m, v);
        }
        #pragma unroll
        for (int o = 32; o; o >>= 1) m = fmaxf(m, __shfl_xor(m, o));
        float denom = 0.f;
        for (int i = beg + lane; i < end; i += 64) {
            int s = srcs[i];
            float v = alpha_s[s] + ad; v = v > 0.f ? v : 0.2f * v;
            denom += __expf(v - m);
        }
        #pragma unroll
        for (int o = 32; o; o >>= 1) denom += __shfl_xor(denom, o);
        float2 acc = {0.f, 0.f};
        for (int i = beg; i < end; ++i) {
            int s = srcs[i];
            float v = alpha_s[s] + ad; v = v > 0.f ? v : 0.2f * v;
            float wgt = __expf(v - m);
            union { unsigned int x; __half2 h; } U;
            U.x = ((const unsigned int*)(XPH + (size_t)s * D))[lane];
            float2 f = __half22float2(U.h);
            acc.x += wgt * f.x; acc.y += wgt * f.y;
        }
        float inv = 1.f / (denom + 1e-16f);
        fin.x = acc.x * inv;
        fin.y = acc.y * inv;
    }

    float2 b2 = ((const float2*)bias)[lane];
    fin.x += b2.x;
    fin.y += b2.y;
    if (GELU) { fin.x = gelu_fast(fin.x); fin.y = gelu_fast(fin.y); }

    if (OUT32) {
        ((float2*)((float*)outp + (size_t)n * D))[lane] = fin;
    } else {
        ((__half2*)((__half*)outp + (size_t)n * D))[lane] = __floats2half2_rn(fin.x, fin.y);
    }
}

// ---------------- launch ----------------

extern "C" void kernel_launch(void* const* d_in, const int* in_sizes, int n_in,
                              void* d_out, int out_size, void* d_ws, size_t ws_size,
                              hipStream_t stream) {
    const float* x    = (const float*)d_in[0];
    const int*   ei   = (const int*)d_in[1];
    const float* W    = (const float*)d_in[2];
    const float* asrc = (const float*)d_in[3];
    const float* adst = (const float*)d_in[4];
    const float* bias = (const float*)d_in[5];
    float* out = (float*)d_out;

    const int* src_arr = ei;
    const int* dst_arr = ei + NE;

    char* ws = (char*)d_ws;
    size_t off = 0;
    auto alloc = [&](size_t bytes) { char* p = ws + off; off += (bytes + 255) & ~(size_t)255; return p; };
    __half* th_a    = (__half*)alloc((size_t)NN * D * sizeof(__half));
    __half* th_b    = (__half*)alloc((size_t)NN * D * sizeof(__half));
    __half* xph     = (__half*)alloc((size_t)NN * D * sizeof(__half));
    __half* wt      = (__half*)alloc((size_t)3 * D * D * sizeof(__half));
    float*  as_a    = (float*)alloc(NN * sizeof(float));
    float*  ad_a    = (float*)alloc(NN * sizeof(float));
    float*  wasd    = (float*)alloc(3 * 256 * sizeof(float));
    int* counts    = (int*)alloc(NN * sizeof(int));
    int* row_ptr   = (int*)alloc((NN + 1) * sizeof(int));
    int* blk_sums  = (int*)alloc(NB * sizeof(int));
    int* srcs      = (int*)alloc((size_t)ETOT * sizeof(int));
    unsigned int*  counts8 = (unsigned int*)alloc((size_t)HB * NNP);
    unsigned char* boff8   = (unsigned char*)alloc((size_t)HB * NNP);
    unsigned char* rank8   = (unsigned char*)alloc((size_t)HB * EPB);
    (void)ws_size; (void)in_sizes; (void)n_in; (void)out_size;

    // 0: init (wasd | wt)
    init_k<<<3 + 192, 256, 0, stream>>>(W, asrc, adst, wasd, wt);
    // 1: LDS histogram + ranks | gemm-0 (hidden under hist)
    histg_k<<<HB + 392, 256, 0, stream>>>(dst_arr, rank8, counts8,
                                          x, wt, wasd, xph, as_a, ad_a);
    // 2: per-dst prefix over partitions
    merge_k<<<(NN + 63) / 64, 256, 0, stream>>>((const unsigned char*)counts8, boff8, counts);
    // 3-4: row_ptr scans
    scan1_k<<<NB, 256, 0, stream>>>(counts, blk_sums);
    scan23_k<<<NB, 256, 0, stream>>>(counts, blk_sums, row_ptr);
    // 5: scatter (standalone, full occupancy)
    scatter2_k<<<HB, 256, 0, stream>>>(src_arr, dst_arr, rank8, boff8, row_ptr, srcs);

    int ab = NN / 4;   // 12500

    // layer 0
    agg_u_k<0, 1><<<ab, 256, 0, stream>>>(row_ptr, srcs, as_a, ad_a, xph, bias, th_b);
    // layer 1
    gemm_k<<<392, 256, 0, stream>>>(th_b, wt + 16384, wasd + 256, xph, as_a, ad_a);
    agg_u_k<0, 1><<<ab, 256, 0, stream>>>(row_ptr, srcs, as_a, ad_a, xph, bias + D, th_a);
    // layer 2
    gemm_k<<<392, 256, 0, stream>>>(th_a, wt + 32768, wasd + 512, xph, as_a, ad_a);
    agg_u_k<1, 0><<<ab, 256, 0, stream>>>(row_ptr, srcs, as_a, ad_a, xph, bias + 2 * D, out);
}

// Round 18
// 185.759 us; speedup vs baseline: 1.0131x; 1.0131x over previous
//
#include <hip/hip_runtime.h>
#include <hip/hip_bf16.h>
#include <hip/hip_fp16.h>

#define NN    50000
#define NE    800000
#define ETOT  (NE + NN)
#define D     128
#define NB    ((NN + 255) / 256)     // 196 scan blocks
#define HB    256                    // hist/scatter partitions
#define EPB   3328                   // edges per partition = 13*256; HB*EPB >= ETOT
#define NNP   50176                  // padded per-partition table stride (bytes)
#define NNPW  (NNP / 4)              // u32 words per histogram row

typedef _Float16 f16x8 __attribute__((ext_vector_type(8)));
typedef float    f32x4 __attribute__((ext_vector_type(4)));

__device__ __forceinline__ float gelu_fast(float x) {
    float x2 = x * x;
    float z2 = x * fmaf(x2, 0.07135483f, 1.5957691f);   // 2z
    float e  = __expf(z2);
    return x - __fdividef(x, e + 1.0f);
}

// v_fma_mix_f32: acc += (f32)f16(lo/hi of HH) * WW
#define FMAMIX_LO(ACC, HH, WW) \
    asm("v_fma_mix_f32 %0, %1, %2, %0 op_sel_hi:[1,0,0]" : "+v"(ACC) : "v"(HH), "v"(WW))
#define FMAMIX_HI(ACC, HH, WW) \
    asm("v_fma_mix_f32 %0, %1, %2, %0 op_sel:[1,0,0] op_sel_hi:[1,0,0]" : "+v"(ACC) : "v"(HH), "v"(WW))

// ---------------- init: wasd | W^T fp16 | zero blk_sums ----------------

__global__ __launch_bounds__(256) void init_k(
        const float* __restrict__ W,
        const float* __restrict__ asrc, const float* __restrict__ adst,
        float* __restrict__ wasd, __half* __restrict__ WT, int* __restrict__ blk_sums) {
    int b = blockIdx.x, t = threadIdx.x;
    if (b < 3) {
        int l = b;
        int k = t & 127, which = t >> 7;
        const float* wr = W + (size_t)l * 16384 + (size_t)k * 128;
        const float* av = (which ? adst : asrc) + (size_t)l * 128;
        float s = 0.f;
        #pragma unroll 4
        for (int c = 0; c < 128; ++c) s += wr[c] * av[c];
        wasd[l * 256 + which * 128 + k] = s;
    } else if (b == 3) {
        if (t < NB) blk_sums[t] = 0;
    } else {
        int i = (b - 4) * 256 + t;           // 0..49151
        int l = i >> 14, r = i & 16383;
        int k = r >> 7, c = r & 127;
        WT[(size_t)l * 16384 + (size_t)c * 128 + k] =
            __float2half_rn(W[(size_t)l * 16384 + (size_t)k * 128 + c]);
    }
}

// ------------- gemm core: MFMA fp16, full [NN][128] output, fused alphas -------------

template <int AIN32>
__device__ __forceinline__ void gemm_body(
        int b2, int t, const void* __restrict__ A, const __half* __restrict__ WT,
        const float* __restrict__ wasd, __half* __restrict__ XP,
        float* __restrict__ alpha_s, float* __restrict__ alpha_d, __half* Bs) {
    #pragma unroll
    for (int it = 0; it < 8; ++it) {
        int bb = it * 4096 + t * 16;
        int c = bb >> 8;
        int swz = bb ^ ((c & 7) << 4);
        *(uint4*)((char*)Bs + swz) = *(const uint4*)((const char*)WT + bb);
    }
    __syncthreads();

    int w = t >> 6, lane = t & 63;
    int r0 = (b2 >> 1) * 256 + w * 64;
    int c0 = (b2 & 1) * 64;
    int lr = lane & 15, lg = lane >> 4;
    bool doalpha = (b2 & 1) == 0;

    f32x4 acc[4][4];
    #pragma unroll
    for (int i = 0; i < 4; ++i)
        #pragma unroll
        for (int j = 0; j < 4; ++j)
            acc[i][j] = (f32x4){0.f, 0.f, 0.f, 0.f};

    float ps[4] = {0, 0, 0, 0}, pd[4] = {0, 0, 0, 0};

    #pragma unroll
    for (int ks = 0; ks < 4; ++ks) {
        f16x8 bf[4];
        #pragma unroll
        for (int ct = 0; ct < 4; ++ct) {
            int c  = c0 + ct * 16 + lr;
            int kb = ks * 64 + lg * 16;
            int addr = c * 256 + (kb ^ ((c & 7) << 4));
            bf[ct] = *(const f16x8*)((const char*)Bs + addr);
        }
        float4 s0, s1, d0, d1;
        if (doalpha) {
            const float* wsp = wasd + ks * 32 + lg * 8;
            s0 = *(const float4*)(wsp);       s1 = *(const float4*)(wsp + 4);
            d0 = *(const float4*)(wsp + 128); d1 = *(const float4*)(wsp + 132);
        }
        #pragma unroll
        for (int rt = 0; rt < 4; ++rt) {
            int row = r0 + rt * 16 + lr;
            int rc  = row < NN ? row : NN - 1;
            f16x8 af;
            float4 f0, f1;
            if (AIN32) {
                const float* ap = (const float*)A + (size_t)rc * D + ks * 32 + lg * 8;
                f0 = *(const float4*)ap;
                f1 = *(const float4*)(ap + 4);
                af[0] = (_Float16)f0.x; af[1] = (_Float16)f0.y;
                af[2] = (_Float16)f0.z; af[3] = (_Float16)f0.w;
                af[4] = (_Float16)f1.x; af[5] = (_Float16)f1.y;
                af[6] = (_Float16)f1.z; af[7] = (_Float16)f1.w;
            } else {
                af = *(const f16x8*)((const char*)A + (size_t)rc * 256 + ks * 64 + lg * 16);
                if (doalpha) {
                    f0 = make_float4((float)af[0], (float)af[1], (float)af[2], (float)af[3]);
                    f1 = make_float4((float)af[4], (float)af[5], (float)af[6], (float)af[7]);
                }
            }
            if (doalpha) {
                ps[rt] += f0.x*s0.x + f0.y*s0.y + f0.z*s0.z + f0.w*s0.w
                        + f1.x*s1.x + f1.y*s1.y + f1.z*s1.z + f1.w*s1.w;
                pd[rt] += f0.x*d0.x + f0.y*d0.y + f0.z*d0.z + f0.w*d0.w
                        + f1.x*d1.x + f1.y*d1.y + f1.z*d1.z + f1.w*d1.w;
            }
            #pragma unroll
            for (int ct = 0; ct < 4; ++ct)
                acc[rt][ct] = __builtin_amdgcn_mfma_f32_16x16x32_f16(
                                  af, bf[ct], acc[rt][ct], 0, 0, 0);
        }
    }

    #pragma unroll
    for (int rt = 0; rt < 4; ++rt) {
        #pragma unroll
        for (int q = 0; q < 4; ++q) {
            int row = r0 + rt * 16 + lg * 4 + q;
            if (row < NN) {
                #pragma unroll
                for (int ct = 0; ct < 4; ++ct)
                    XP[(size_t)row * D + c0 + ct * 16 + lr] = __float2half_rn(acc[rt][ct][q]);
            }
        }
    }

    if (doalpha) {
        #pragma unroll
        for (int rt = 0; rt < 4; ++rt) {
            float p = ps[rt], dq = pd[rt];
            p  += __shfl_xor(p, 16);  p  += __shfl_xor(p, 32);
            dq += __shfl_xor(dq, 16); dq += __shfl_xor(dq, 32);
            int row = r0 + rt * 16 + lr;
            if (lane < 16 && row < NN) { alpha_s[row] = p; alpha_d[row] = dq; }
        }
    }
}

// ------- histg: LDS-privatized histogram (blocks < HB) | gemm-0 (blocks >= HB) -------

__global__ __launch_bounds__(256) void histg_k(
        const int* __restrict__ dst_arr, unsigned char* __restrict__ rank8,
        unsigned int* __restrict__ counts8,
        const float* __restrict__ x, const __half* __restrict__ WT,
        const float* __restrict__ wasd, __half* __restrict__ XPH,
        float* __restrict__ alpha_s, float* __restrict__ alpha_d) {
    __shared__ __align__(16) unsigned char shmem[NNPW * 4];   // 49 KB (hist) / 32 KB (gemm)
    int b = blockIdx.x, t = threadIdx.x;
    if (b < HB) {
        unsigned int* h = (unsigned int*)shmem;
        for (int i = t; i < NNPW; i += 256) h[i] = 0u;
        __syncthreads();
        int base = b * EPB;
        #pragma unroll
        for (int it = 0; it < 13; ++it) {
            int e = base + it * 256 + t;
            if (e < ETOT) {
                int d = (e < NE) ? dst_arr[e] : (e - NE);
                int sh = (d & 3) * 8;
                unsigned int old = atomicAdd(&h[d >> 2], 1u << sh);
                rank8[e] = (unsigned char)((old >> sh) & 0xffu);
            }
        }
        __syncthreads();
        unsigned int* crow = counts8 + (size_t)b * NNPW;
        for (int i = t; i < NNPW; i += 256) crow[i] = h[i];
    } else {
        gemm_body<1>(b - HB, t, x, WT, wasd, XPH, alpha_s, alpha_d, (__half*)shmem);
    }
}

// ------- merge: per-dst prefix over partitions -> boff8, totals -> counts, blk_sums -------

__global__ __launch_bounds__(256) void merge_k(
        const unsigned char* __restrict__ counts8, unsigned char* __restrict__ boff8,
        int* __restrict__ counts, int* __restrict__ blk_sums) {
    __shared__ int segtot[4][64];
    int t = threadIdx.x;
    int dl = t & 63, seg = t >> 6;
    int d = blockIdx.x * 64 + dl;
    const unsigned char* cp = counts8 + (size_t)seg * 64 * NNP + d;
    int partial = 0;
    #pragma unroll 8
    for (int p = 0; p < 64; ++p) partial += (int)cp[(size_t)p * NNP];
    segtot[seg][dl] = partial;
    __syncthreads();
    int base = 0;
    if (seg > 0) base += segtot[0][dl];
    if (seg > 1) base += segtot[1][dl];
    if (seg > 2) base += segtot[2][dl];
    unsigned char* bp = boff8 + (size_t)seg * 64 * NNP + d;
    int acc = base;
    for (int p = 0; p < 64; ++p) {
        bp[(size_t)p * NNP] = (unsigned char)acc;
        acc += (int)cp[(size_t)p * NNP];
    }
    if (seg == 3 && d < NN) counts[d] = acc;
    // fused scan1: accumulate this block's 64-dst total into its scan-block sum
    if (seg == 3) {
        int tot = (d < NN) ? acc : 0;
        #pragma unroll
        for (int o = 32; o; o >>= 1) tot += __shfl_xor(tot, o);
        if (dl == 0) atomicAdd(&blk_sums[blockIdx.x >> 2], tot);
    }
}

// ---------------- scan (fused 2+3) ----------------

__global__ void scan23_k(const int* __restrict__ counts, const int* __restrict__ blk_sums,
                         int* __restrict__ row_ptr) {
    __shared__ int s[256];
    __shared__ int boff_sh;
    int t = threadIdx.x, bid = blockIdx.x;
    if (t < 64) {
        int acc = 0;
        for (int i = t; i < bid; i += 64) acc += blk_sums[i];
        #pragma unroll
        for (int o = 32; o; o >>= 1) acc += __shfl_xor(acc, o);
        if (t == 0) boff_sh = acc;
    }
    __syncthreads();
    int boff = boff_sh;
    int i = bid * 256 + t;
    int v = (i < NN) ? counts[i] : 0;
    s[t] = v;
    __syncthreads();
    for (int off = 1; off < 256; off <<= 1) {
        int x = (t >= off) ? s[t - off] : 0;
        __syncthreads();
        s[t] += x;
        __syncthreads();
    }
    int excl = s[t] - v + boff;
    if (i < NN) row_ptr[i] = excl;
    if (bid == NB - 1 && t == 255) row_ptr[NN] = s[255] + boff;
}

// ---------------- scatter: standalone, atomic-free, full occupancy ----------------

__global__ __launch_bounds__(256) void scatter2_k(
        const int* __restrict__ src_arr, const int* __restrict__ dst_arr,
        const unsigned char* __restrict__ rank8, const unsigned char* __restrict__ boff8,
        const int* __restrict__ row_ptr, int* __restrict__ srcs) {
    int b = blockIdx.x, t = threadIdx.x;
    const unsigned char* brow = boff8 + (size_t)b * NNP;
    int base = b * EPB;
    #pragma unroll
    for (int it = 0; it < 13; ++it) {
        int e = base + it * 256 + t;
        if (e < ETOT) {
            int d, s;
            if (e < NE) { d = dst_arr[e]; s = src_arr[e]; }
            else        { d = e - NE;    s = e - NE; }
            srcs[row_ptr[d] + (int)brow[d] + (int)rank8[e]] = s;
        }
    }
}

// ---------------- standalone gemm (layers 1, 2) ----------------

__global__ __launch_bounds__(256) void gemm_k(
        const __half* __restrict__ TH, const __half* __restrict__ WT,
        const float* __restrict__ wasd, __half* __restrict__ XPH,
        float* __restrict__ alpha_s, float* __restrict__ alpha_d) {
    __shared__ __half Bs[D * D];
    gemm_body<0>(blockIdx.x, threadIdx.x, TH, WT, wasd, XPH, alpha_s, alpha_d, Bs);
}

// ------- aggregation (R16-proven): gather fp16 [NN][128], 4-deep pipelined, fma_mix ----

template <int OUT32, int GELU>
__global__ __launch_bounds__(256) void agg_u_k(
        const int* __restrict__ row_ptr, const int* __restrict__ srcs,
        const float* __restrict__ alpha_s, const float* __restrict__ alpha_d,
        const __half* __restrict__ XPH, const float* __restrict__ bias,
        void* __restrict__ outp) {
    __shared__ float xch[4][128];
    int wv = threadIdx.x >> 6;
    int n = (blockIdx.x * blockDim.x + threadIdx.x) >> 6;
    int lane = threadIdx.x & 63;
    int beg = row_ptr[n], end = row_ptr[n + 1], deg = end - beg;
    float ad = alpha_d[n];
    int qw = lane >> 4, q = lane & 15;

    float2 fin;

    if (deg <= 64) {
        int sreg = 0;
        float e = -3.4e38f;
        if (lane < deg) {
            sreg = srcs[beg + lane];
            float v = alpha_s[sreg] + ad;
            e = v > 0.f ? v : 0.2f * v;
        }
        float m = e;
        #pragma unroll
        for (int o = 32; o; o >>= 1) m = fmaxf(m, __shfl_xor(m, o));
        float w = (lane < deg) ? __expf(e - m) : 0.f;
        float denom = w;
        #pragma unroll
        for (int o = 32; o; o >>= 1) denom += __shfl_xor(denom, o);

        float acc[8] = {0,0,0,0,0,0,0,0};
        int dgr = (deg + 3) & ~3;
        const char* xb = (const char*)XPH;
        int qb = q << 4;
        int j = 0;
        #define PROC(UU, WW)                                                      \
            {                                                                     \
                FMAMIX_LO(acc[0], (UU).x, (WW)); FMAMIX_HI(acc[1], (UU).x, (WW)); \
                FMAMIX_LO(acc[2], (UU).y, (WW)); FMAMIX_HI(acc[3], (UU).y, (WW)); \
                FMAMIX_LO(acc[4], (UU).z, (WW)); FMAMIX_HI(acc[5], (UU).z, (WW)); \
                FMAMIX_LO(acc[6], (UU).w, (WW)); FMAMIX_HI(acc[7], (UU).w, (WW)); \
            }
        for (; j + 16 <= dgr; j += 16) {
            int   s0 = __shfl(sreg, j + qw);       float w0 = __shfl(w, j + qw);
            int   s1 = __shfl(sreg, j + 4 + qw);   float w1 = __shfl(w, j + 4 + qw);
            int   s2 = __shfl(sreg, j + 8 + qw);   float w2 = __shfl(w, j + 8 + qw);
            int   s3 = __shfl(sreg, j + 12 + qw);  float w3 = __shfl(w, j + 12 + qw);
            uint4 u0 = *(const uint4*)(xb + ((s0 << 8) + qb));
            uint4 u1 = *(const uint4*)(xb + ((s1 << 8) + qb));
            uint4 u2 = *(const uint4*)(xb + ((s2 << 8) + qb));
            uint4 u3 = *(const uint4*)(xb + ((s3 << 8) + qb));
            PROC(u0, w0) PROC(u1, w1) PROC(u2, w2) PROC(u3, w3)
        }
        for (; j < dgr; j += 4) {
            int   s0 = __shfl(sreg, j + qw);
            float w0 = __shfl(w, j + qw);
            uint4 u0 = *(const uint4*)(xb + ((s0 << 8) + qb));
            PROC(u0, w0)
        }
        #undef PROC
        #pragma unroll
        for (int f = 0; f < 8; ++f) {
            acc[f] += __shfl_xor(acc[f], 16);
            acc[f] += __shfl_xor(acc[f], 32);
        }
        if (lane < 16) {
            float4* p = (float4*)&xch[wv][q * 8];
            p[0] = make_float4(acc[0], acc[1], acc[2], acc[3]);
            p[1] = make_float4(acc[4], acc[5], acc[6], acc[7]);
        }
        __asm__ volatile("s_waitcnt lgkmcnt(0)" ::: "memory");
        __builtin_amdgcn_sched_barrier(0);
        float2 a2 = *(const float2*)&xch[wv][2 * lane];
        float inv = 1.f / (denom + 1e-16f);
        fin.x = a2.x * inv;
        fin.y = a2.y * inv;
    } else {
        float m = -3.4e38f;
        for (int i = beg + lane; i < end; i += 64) {
            int s = srcs[i];
            float v = alpha_s[s] + ad; v = v > 0.f ? v : 0.2f * v;
            m = fmaxf(m, v);
        }
        #pragma unroll
        for (int o = 32; o; o >>= 1) m = fmaxf(m, __shfl_xor(m, o));
        float denom = 0.f;
        for (int i = beg + lane; i < end; i += 64) {
            int s = srcs[i];
            float v = alpha_s[s] + ad; v = v > 0.f ? v : 0.2f * v;
            denom += __expf(v - m);
        }
        #pragma unroll
        for (int o = 32; o; o >>= 1) denom += __shfl_xor(denom, o);
        float2 acc = {0.f, 0.f};
        for (int i = beg; i < end; ++i) {
            int s = srcs[i];
            float v = alpha_s[s] + ad; v = v > 0.f ? v : 0.2f * v;
            float wgt = __expf(v - m);
            union { unsigned int x; __half2 h; } U;
            U.x = ((const unsigned int*)(XPH + (size_t)s * D))[lane];
            float2 f = __half22float2(U.h);
            acc.x += wgt * f.x; acc.y += wgt * f.y;
        }
        float inv = 1.f / (denom + 1e-16f);
        fin.x = acc.x * inv;
        fin.y = acc.y * inv;
    }

    float2 b2 = ((const float2*)bias)[lane];
    fin.x += b2.x;
    fin.y += b2.y;
    if (GELU) { fin.x = gelu_fast(fin.x); fin.y = gelu_fast(fin.y); }

    if (OUT32) {
        ((float2*)((float*)outp + (size_t)n * D))[lane] = fin;
    } else {
        ((__half2*)((__half*)outp + (size_t)n * D))[lane] = __floats2half2_rn(fin.x, fin.y);
    }
}

// ---------------- launch ----------------

extern "C" void kernel_launch(void* const* d_in, const int* in_sizes, int n_in,
                              void* d_out, int out_size, void* d_ws, size_t ws_size,
                              hipStream_t stream) {
    const float* x    = (const float*)d_in[0];
    const int*   ei   = (const int*)d_in[1];
    const float* W    = (const float*)d_in[2];
    const float* asrc = (const float*)d_in[3];
    const float* adst = (const float*)d_in[4];
    const float* bias = (const float*)d_in[5];
    float* out = (float*)d_out;

    const int* src_arr = ei;
    const int* dst_arr = ei + NE;

    char* ws = (char*)d_ws;
    size_t off = 0;
    auto alloc = [&](size_t bytes) { char* p = ws + off; off += (bytes + 255) & ~(size_t)255; return p; };
    __half* th_a    = (__half*)alloc((size_t)NN * D * sizeof(__half));
    __half* th_b    = (__half*)alloc((size_t)NN * D * sizeof(__half));
    __half* xph     = (__half*)alloc((size_t)NN * D * sizeof(__half));
    __half* wt      = (__half*)alloc((size_t)3 * D * D * sizeof(__half));
    float*  as_a    = (float*)alloc(NN * sizeof(float));
    float*  ad_a    = (float*)alloc(NN * sizeof(float));
    float*  wasd    = (float*)alloc(3 * 256 * sizeof(float));
    int* counts    = (int*)alloc(NN * sizeof(int));
    int* row_ptr   = (int*)alloc((NN + 1) * sizeof(int));
    int* blk_sums  = (int*)alloc(NB * sizeof(int));
    int* srcs      = (int*)alloc((size_t)ETOT * sizeof(int));
    unsigned int*  counts8 = (unsigned int*)alloc((size_t)HB * NNP);
    unsigned char* boff8   = (unsigned char*)alloc((size_t)HB * NNP);
    unsigned char* rank8   = (unsigned char*)alloc((size_t)HB * EPB);
    (void)ws_size; (void)in_sizes; (void)n_in; (void)out_size;

    // 0: init (wasd | blk_sums zero | wt)
    init_k<<<4 + 192, 256, 0, stream>>>(W, asrc, adst, wasd, wt, blk_sums);
    // 1: LDS histogram + ranks | gemm-0 (hidden under hist)
    histg_k<<<HB + 392, 256, 0, stream>>>(dst_arr, rank8, counts8,
                                          x, wt, wasd, xph, as_a, ad_a);
    // 2: per-dst prefix over partitions (+ fused scan1 via atomics)
    merge_k<<<(NN + 63) / 64, 256, 0, stream>>>((const unsigned char*)counts8, boff8,
                                                counts, blk_sums);
    // 3: row_ptr scan
    scan23_k<<<NB, 256, 0, stream>>>(counts, blk_sums, row_ptr);
    // 4: scatter (standalone, full occupancy)
    scatter2_k<<<HB, 256, 0, stream>>>(src_arr, dst_arr, rank8, boff8, row_ptr, srcs);

    int ab = NN / 4;   // 12500

    // layer 0
    agg_u_k<0, 1><<<ab, 256, 0, stream>>>(row_ptr, srcs, as_a, ad_a, xph, bias, th_b);
    // layer 1
    gemm_k<<<392, 256, 0, stream>>>(th_b, wt + 16384, wasd + 256, xph, as_a, ad_a);
    agg_u_k<0, 1><<<ab, 256, 0, stream>>>(row_ptr, srcs, as_a, ad_a, xph, bias + D, th_a);
    // layer 2
    gemm_k<<<392, 256, 0, stream>>>(th_a, wt + 32768, wasd + 512, xph, as_a, ad_a);
    agg_u_k<1, 0><<<ab, 256, 0, stream>>>(row_ptr, srcs, as_a, ad_a, xph, bias + 2 * D, out);
}